// Round 1
// baseline (118.293 us; speedup 1.0000x reference)
//
#include <hip/hip_runtime.h>
#include <hip/hip_bf16.h>

// LoRAModulatedSchnetInteraction: B=2, A=512, F=128, Rbf=64, R=4
// Strategy:
//  - Fold LoRA into per-batch effective weights: Weff[b] = W + A[b]@B[b]  (prep_weights)
//  - x_i / final two atomwise layers: exact fp32 VALU dense kernels (dense_ssp)
//  - Core: fused per-(b,i) kernel: compact active j (mask), 3-layer bf16-MFMA MLP on
//    f_ij rows, * c_ij * x_i[j,:], masked sum over j -> y[b,i,:]  (schnet_core)

typedef float        f32x4  __attribute__((ext_vector_type(4)));
typedef unsigned int u32x4  __attribute__((ext_vector_type(4)));
typedef unsigned int u32x2  __attribute__((ext_vector_type(2)));
typedef __bf16       bf16x8 __attribute__((ext_vector_type(8)));

__device__ __forceinline__ float ssp_f(float v) {
  // log(0.5*e^v + 0.5)  == softplus(v) - log(2)
  return __logf(0.5f * __expf(v) + 0.5f);
}

__device__ __forceinline__ unsigned short f2bfu(float f) {
  __hip_bfloat16 h = __float2bfloat16(f);
  return __builtin_bit_cast(unsigned short, h);
}

__device__ __forceinline__ u32x4 pack8(f32x4 a, f32x4 b) {
  u32x4 u;
  u.x = (unsigned)f2bfu(a.x) | ((unsigned)f2bfu(a.y) << 16);
  u.y = (unsigned)f2bfu(a.z) | ((unsigned)f2bfu(a.w) << 16);
  u.z = (unsigned)f2bfu(b.x) | ((unsigned)f2bfu(b.y) << 16);
  u.w = (unsigned)f2bfu(b.z) | ((unsigned)f2bfu(b.w) << 16);
  return u;
}

__device__ __forceinline__ f32x4 fzero4() { f32x4 z = {0.f, 0.f, 0.f, 0.f}; return z; }

#define SWZ(j) (((j) & 7) << 4)

// ---------------------------------------------------------------------------
// Weight prep: Weff[b] = W + A[b] @ B[b].
// Filter layers (l=1,2,3) stored TRANSPOSED bf16 [b][nout][din] for MFMA A-frags.
// bc/a0/a1 (l=0,4,5) stored fp32 [b][k][n] for the VALU dense kernels.
// ---------------------------------------------------------------------------
__global__ void prep_weights(
    const float* __restrict__ W_bc, const float* __restrict__ A_bc, const float* __restrict__ B_bc,
    const float* __restrict__ W_f0, const float* __restrict__ A_f0, const float* __restrict__ B_f0,
    const float* __restrict__ W_f1, const float* __restrict__ A_f1, const float* __restrict__ B_f1,
    const float* __restrict__ W_f2, const float* __restrict__ A_f2, const float* __restrict__ B_f2,
    const float* __restrict__ W_a0, const float* __restrict__ A_a0, const float* __restrict__ B_a0,
    const float* __restrict__ W_a1, const float* __restrict__ A_a1, const float* __restrict__ B_a1,
    unsigned short* __restrict__ Wt0, unsigned short* __restrict__ Wt1, unsigned short* __restrict__ Wt2,
    float* __restrict__ Wbc, float* __restrict__ Wa0, float* __restrict__ Wa1)
{
  const int l = blockIdx.y, b = blockIdx.z;
  const int e = blockIdx.x * 256 + threadIdx.x;
  const float *W, *A, *Bm; int din;
  switch (l) {
    case 0:  W = W_bc; A = A_bc; Bm = B_bc; din = 128; break;
    case 1:  W = W_f0; A = A_f0; Bm = B_f0; din = 64;  break;
    case 2:  W = W_f1; A = A_f1; Bm = B_f1; din = 128; break;
    case 3:  W = W_f2; A = A_f2; Bm = B_f2; din = 128; break;
    case 4:  W = W_a0; A = A_a0; Bm = B_a0; din = 128; break;
    default: W = W_a1; A = A_a1; Bm = B_a1; din = 128; break;
  }
  if (e >= din * 128) return;
  const int k = e >> 7, n = e & 127;
  float wv = W[k * 128 + n];
  #pragma unroll
  for (int r = 0; r < 4; ++r)
    wv += A[(b * din + k) * 4 + r] * Bm[(b * 4 + r) * 128 + n];
  if (l == 1)      Wt0[(b * 128 + n) * 64  + k] = f2bfu(wv);
  else if (l == 2) Wt1[(b * 128 + n) * 128 + k] = f2bfu(wv);
  else if (l == 3) Wt2[(b * 128 + n) * 128 + k] = f2bfu(wv);
  else if (l == 0) Wbc[(b * 128 + k) * 128 + n] = wv;
  else if (l == 4) Wa0[(b * 128 + k) * 128 + n] = wv;
  else             Wa1[(b * 128 + k) * 128 + n] = wv;
}

// ---------------------------------------------------------------------------
// dense_ssp: out[row,n] = ssp(sum_k in[row,k]*W[b,k,n] + bias[n]) (+ resid)
// rows = [2*512], fp32 exact. 4 rows per block, 512 threads (1 output each).
// ---------------------------------------------------------------------------
__global__ __launch_bounds__(512) void dense_ssp(
    const float* __restrict__ in, const float* __restrict__ W,
    const float* __restrict__ bias, const float* __restrict__ resid,
    float* __restrict__ out)
{
  __shared__ float in_l[4][128];
  const int t = threadIdx.x;
  const int rg0 = blockIdx.x << 2;        // first global row of block
  const int b = rg0 >> 9;
  in_l[t >> 7][t & 127] = in[rg0 * 128 + t];
  __syncthreads();
  const int j = t >> 7, n = t & 127;
  const float* wp = W + (b << 14) + n;
  const float* ip = in_l[j];
  float acc = 0.f;
  #pragma unroll 8
  for (int k = 0; k < 128; ++k) acc += ip[k] * wp[k << 7];
  float r = ssp_f(acc + bias[n]);
  const int oi = (rg0 + j) * 128 + n;
  if (resid) r += resid[oi];
  out[oi] = r;
}

// ---------------------------------------------------------------------------
// schnet_core: one block per (b,i). 256 threads = 4 waves.
// Wave w owns nout range [w*32, w*32+32) for all GEMMs; all waves span all j.
// Per 64-row j-tile (compacted active j's):
//   stage f(bf16,swizzled LDS) -> G1 -> ssp -> hbuf -> G2 -> ssp -> hbuf
//   -> G3 -> ssp -> acc_y += s_j * xi[j,f] * h3
// All GEMMs in transposed orientation: D = Wt (A, regs) * actT (B, LDS).
// ---------------------------------------------------------------------------
__global__ __launch_bounds__(256, 2) void schnet_core(
    const float* __restrict__ f_ij, const float* __restrict__ c_ij,
    const int* __restrict__ mask,
    const unsigned short* __restrict__ Wt0, const unsigned short* __restrict__ Wt1,
    const unsigned short* __restrict__ Wt2,
    const float* __restrict__ bias0, const float* __restrict__ bias1,
    const float* __restrict__ bias2,
    const float* __restrict__ xi, float* __restrict__ y)
{
  __shared__ __align__(16) unsigned short fbuf[64 * 64];    // [j][k] bf16, swizzled
  __shared__ __align__(16) unsigned short hbuf[64 * 128];   // [j][nout] bf16, swizzled
  __shared__ int   jlist[576];
  __shared__ float slist[576];
  __shared__ int cnt_s[8], base_s[8], nact_s;

  const int tid  = threadIdx.x;
  const int lane = tid & 63;
  const int w    = tid >> 6;
  const int lrow = lane & 15;
  const int lgrp = lane >> 4;
  const int bi   = blockIdx.x;          // b*512 + i
  const int b    = bi >> 9;

  // ---- deterministic mask compaction ----
  const int mb = bi << 9;               // (b*512+i)*512
  const int jA = tid, jB = tid + 256;
  const int   mA = mask[mb + jA]; const float cA = c_ij[mb + jA];
  const int   mB = mask[mb + jB]; const float cB = c_ij[mb + jB];
  unsigned long long balA = __ballot(mA != 0);
  unsigned long long balB = __ballot(mB != 0);
  if (lane == 0) { cnt_s[w] = __popcll(balA); cnt_s[4 + w] = __popcll(balB); }
  __syncthreads();
  if (tid == 0) {
    int s = 0;
    for (int c = 0; c < 8; ++c) { base_s[c] = s; s += cnt_s[c]; }
    nact_s = s;
  }
  __syncthreads();
  const int na = nact_s;
  const unsigned long long lm = (1ull << lane) - 1ull;
  if (mA) { int p = base_s[w]     + __popcll(balA & lm); jlist[p] = jA; slist[p] = cA; }
  if (mB) { int p = base_s[4 + w] + __popcll(balB & lm); jlist[p] = jB; slist[p] = cB; }
  if (tid < 64) { int idx = na + tid; if (idx < 576) { jlist[idx] = 0; slist[idx] = 0.f; } }
  __syncthreads();

  // ---- per-wave weight A-fragments (held in VGPRs) + biases ----
  const int mg = w;
  bf16x8 w0f[2][2], w1f[2][4], w2f[2][4];
  f32x4  bs0[2], bs1[2], bs2[2];
  #pragma unroll
  for (int nt = 0; nt < 2; ++nt) {
    const int nout = mg * 32 + nt * 16 + lrow;
    const int nb0 = (b * 128 + nout) * 64  + lgrp * 8;
    const int nb1 = (b * 128 + nout) * 128 + lgrp * 8;
    #pragma unroll
    for (int ks = 0; ks < 2; ++ks)
      w0f[nt][ks] = *(const bf16x8*)(Wt0 + nb0 + ks * 32);
    #pragma unroll
    for (int ks = 0; ks < 4; ++ks) {
      w1f[nt][ks] = *(const bf16x8*)(Wt1 + nb1 + ks * 32);
      w2f[nt][ks] = *(const bf16x8*)(Wt2 + nb1 + ks * 32);
    }
    const int n0 = mg * 32 + nt * 16 + lgrp * 4;
    bs0[nt] = *(const f32x4*)(bias0 + n0);
    bs1[nt] = *(const f32x4*)(bias1 + n0);
    bs2[nt] = *(const f32x4*)(bias2 + n0);
  }

  float accy[2][4] = {{0.f,0.f,0.f,0.f},{0.f,0.f,0.f,0.f}};
  const float* fbase = f_ij + ((size_t)mb << 6);

  for (int jt0 = 0; jt0 < na; jt0 += 64) {
    // ---- stage f tile: 64 gathered rows x 64 f32 -> bf16 swizzled LDS ----
    {
      const int r = tid >> 2, part = tid & 3;
      const int ja = jlist[jt0 + r];
      const f32x4* src = (const f32x4*)(fbase + ja * 64 + part * 16);
      f32x4 v0 = src[0], v1 = src[1], v2 = src[2], v3 = src[3];
      char* dst = (char*)fbuf + r * 128;
      const int o0 = (part * 32) ^ SWZ(r);
      *(u32x4*)(dst + o0)        = pack8(v0, v1);
      *(u32x4*)(dst + (o0 ^ 16)) = pack8(v2, v3);
    }
    __syncthreads();

    f32x4 acc[2][4];

    // ---- GEMM1: h1^T = Wt0 * f^T (K=64) ----
    #pragma unroll
    for (int nt = 0; nt < 2; ++nt)
      #pragma unroll
      for (int jt = 0; jt < 4; ++jt) acc[nt][jt] = fzero4();
    #pragma unroll
    for (int jt = 0; jt < 4; ++jt) {
      const int j = jt * 16 + lrow;
      const char* rb = (const char*)fbuf + j * 128;
      const int sw = SWZ(j);
      #pragma unroll
      for (int ks = 0; ks < 2; ++ks) {
        bf16x8 bf = *(const bf16x8*)(rb + ((lgrp * 16 + ks * 64) ^ sw));
        acc[0][jt] = __builtin_amdgcn_mfma_f32_16x16x32_bf16(w0f[0][ks], bf, acc[0][jt], 0, 0, 0);
        acc[1][jt] = __builtin_amdgcn_mfma_f32_16x16x32_bf16(w0f[1][ks], bf, acc[1][jt], 0, 0, 0);
      }
    }
    // epilogue 1: ssp -> bf16 -> hbuf
    #pragma unroll
    for (int jt = 0; jt < 4; ++jt) {
      const int j = jt * 16 + lrow;
      char* rb = (char*)hbuf + j * 256;
      const int sw = SWZ(j);
      #pragma unroll
      for (int nt = 0; nt < 2; ++nt) {
        const int n0 = mg * 32 + nt * 16 + lgrp * 4;
        float e0 = ssp_f(acc[nt][jt].x + bs0[nt].x);
        float e1 = ssp_f(acc[nt][jt].y + bs0[nt].y);
        float e2 = ssp_f(acc[nt][jt].z + bs0[nt].z);
        float e3 = ssp_f(acc[nt][jt].w + bs0[nt].w);
        u32x2 pk;
        pk.x = (unsigned)f2bfu(e0) | ((unsigned)f2bfu(e1) << 16);
        pk.y = (unsigned)f2bfu(e2) | ((unsigned)f2bfu(e3) << 16);
        *(u32x2*)(rb + ((n0 * 2) ^ sw)) = pk;
      }
    }
    __syncthreads();

    // ---- GEMM2: h2^T = Wt1 * h1^T (K=128) ----
    #pragma unroll
    for (int nt = 0; nt < 2; ++nt)
      #pragma unroll
      for (int jt = 0; jt < 4; ++jt) acc[nt][jt] = fzero4();
    #pragma unroll
    for (int jt = 0; jt < 4; ++jt) {
      const int j = jt * 16 + lrow;
      const char* rb = (const char*)hbuf + j * 256;
      const int sw = SWZ(j);
      #pragma unroll
      for (int ks = 0; ks < 4; ++ks) {
        bf16x8 bf = *(const bf16x8*)(rb + ((lgrp * 16 + ks * 64) ^ sw));
        acc[0][jt] = __builtin_amdgcn_mfma_f32_16x16x32_bf16(w1f[0][ks], bf, acc[0][jt], 0, 0, 0);
        acc[1][jt] = __builtin_amdgcn_mfma_f32_16x16x32_bf16(w1f[1][ks], bf, acc[1][jt], 0, 0, 0);
      }
    }
    __syncthreads();   // all h1 reads done before overwrite
    // epilogue 2: ssp -> bf16 -> hbuf
    #pragma unroll
    for (int jt = 0; jt < 4; ++jt) {
      const int j = jt * 16 + lrow;
      char* rb = (char*)hbuf + j * 256;
      const int sw = SWZ(j);
      #pragma unroll
      for (int nt = 0; nt < 2; ++nt) {
        const int n0 = mg * 32 + nt * 16 + lgrp * 4;
        float e0 = ssp_f(acc[nt][jt].x + bs1[nt].x);
        float e1 = ssp_f(acc[nt][jt].y + bs1[nt].y);
        float e2 = ssp_f(acc[nt][jt].z + bs1[nt].z);
        float e3 = ssp_f(acc[nt][jt].w + bs1[nt].w);
        u32x2 pk;
        pk.x = (unsigned)f2bfu(e0) | ((unsigned)f2bfu(e1) << 16);
        pk.y = (unsigned)f2bfu(e2) | ((unsigned)f2bfu(e3) << 16);
        *(u32x2*)(rb + ((n0 * 2) ^ sw)) = pk;
      }
    }
    __syncthreads();

    // ---- GEMM3: h3^T = Wt2 * h2^T (K=128) ----
    #pragma unroll
    for (int nt = 0; nt < 2; ++nt)
      #pragma unroll
      for (int jt = 0; jt < 4; ++jt) acc[nt][jt] = fzero4();
    #pragma unroll
    for (int jt = 0; jt < 4; ++jt) {
      const int j = jt * 16 + lrow;
      const char* rb = (const char*)hbuf + j * 256;
      const int sw = SWZ(j);
      #pragma unroll
      for (int ks = 0; ks < 4; ++ks) {
        bf16x8 bf = *(const bf16x8*)(rb + ((lgrp * 16 + ks * 64) ^ sw));
        acc[0][jt] = __builtin_amdgcn_mfma_f32_16x16x32_bf16(w2f[0][ks], bf, acc[0][jt], 0, 0, 0);
        acc[1][jt] = __builtin_amdgcn_mfma_f32_16x16x32_bf16(w2f[1][ks], bf, acc[1][jt], 0, 0, 0);
      }
    }
    // epilogue 3: ssp; acc_y += s_j * xi[j,f] * h3
    #pragma unroll
    for (int jt = 0; jt < 4; ++jt) {
      const int jj = jt * 16 + lrow;
      const float s  = slist[jt0 + jj];
      const int   ja = jlist[jt0 + jj];
      const float* xr = xi + (((b << 9) + ja) << 7);
      #pragma unroll
      for (int nt = 0; nt < 2; ++nt) {
        const int n0 = mg * 32 + nt * 16 + lgrp * 4;
        f32x4 xv = *(const f32x4*)(xr + n0);
        float h0 = ssp_f(acc[nt][jt].x + bs2[nt].x);
        float h1 = ssp_f(acc[nt][jt].y + bs2[nt].y);
        float h2 = ssp_f(acc[nt][jt].z + bs2[nt].z);
        float h3 = ssp_f(acc[nt][jt].w + bs2[nt].w);
        accy[nt][0] += s * xv.x * h0;
        accy[nt][1] += s * xv.y * h1;
        accy[nt][2] += s * xv.z * h2;
        accy[nt][3] += s * xv.w * h3;
      }
    }
  }

  // ---- reduce over the 16 j-sub-lanes; write y[b,i,:] ----
  #pragma unroll
  for (int d = 1; d < 16; d <<= 1)
    #pragma unroll
    for (int nt = 0; nt < 2; ++nt)
      #pragma unroll
      for (int r = 0; r < 4; ++r)
        accy[nt][r] += __shfl_xor(accy[nt][r], d, 64);
  if (lrow == 0) {
    float* yo = y + ((size_t)bi << 7);
    #pragma unroll
    for (int nt = 0; nt < 2; ++nt) {
      const int n0 = mg * 32 + nt * 16 + lgrp * 4;
      f32x4 v = {accy[nt][0], accy[nt][1], accy[nt][2], accy[nt][3]};
      *(f32x4*)(yo + n0) = v;
    }
  }
}

// ---------------------------------------------------------------------------
extern "C" void kernel_launch(void* const* d_in, const int* in_sizes, int n_in,
                              void* d_out, int out_size, void* d_ws, size_t ws_size,
                              hipStream_t stream)
{
  const float* x    = (const float*)d_in[0];
  const float* f_ij = (const float*)d_in[1];
  const float* c_ij = (const float*)d_in[2];
  const int*   mask = (const int*)d_in[3];
  const float* W_bc = (const float*)d_in[4];
  const float* b_bc = (const float*)d_in[5];
  const float* A_bc = (const float*)d_in[6];
  const float* B_bc = (const float*)d_in[7];
  const float* W_f0 = (const float*)d_in[8];
  const float* b_f0 = (const float*)d_in[9];
  const float* A_f0 = (const float*)d_in[10];
  const float* B_f0 = (const float*)d_in[11];
  const float* W_f1 = (const float*)d_in[12];
  const float* b_f1 = (const float*)d_in[13];
  const float* A_f1 = (const float*)d_in[14];
  const float* B_f1 = (const float*)d_in[15];
  const float* W_f2 = (const float*)d_in[16];
  const float* b_f2 = (const float*)d_in[17];
  const float* A_f2 = (const float*)d_in[18];
  const float* B_f2 = (const float*)d_in[19];
  const float* W_a0 = (const float*)d_in[20];
  const float* b_a0 = (const float*)d_in[21];
  const float* A_a0 = (const float*)d_in[22];
  const float* B_a0 = (const float*)d_in[23];
  const float* W_a1 = (const float*)d_in[24];
  const float* b_a1 = (const float*)d_in[25];
  const float* A_a1 = (const float*)d_in[26];
  const float* B_a1 = (const float*)d_in[27];
  float* out = (float*)d_out;

  char* ws = (char*)d_ws;
  unsigned short* Wt0 = (unsigned short*)(ws);            //  32768 B
  unsigned short* Wt1 = (unsigned short*)(ws + 32768);    //  65536 B
  unsigned short* Wt2 = (unsigned short*)(ws + 98304);    //  65536 B
  float* Wbc = (float*)(ws + 163840);                     // 131072 B
  float* Wa0 = (float*)(ws + 294912);                     // 131072 B
  float* Wa1 = (float*)(ws + 425984);                     // 131072 B
  float* xi  = (float*)(ws + 557056);                     // 524288 B
  float* yb  = (float*)(ws + 1081344);                    // 524288 B
  float* y1  = (float*)(ws + 1605632);                    // 524288 B  (total ~2.03 MB)

  prep_weights<<<dim3(64, 6, 2), 256, 0, stream>>>(
      W_bc, A_bc, B_bc, W_f0, A_f0, B_f0, W_f1, A_f1, B_f1,
      W_f2, A_f2, B_f2, W_a0, A_a0, B_a0, W_a1, A_a1, B_a1,
      Wt0, Wt1, Wt2, Wbc, Wa0, Wa1);

  dense_ssp<<<256, 512, 0, stream>>>(x, Wbc, b_bc, nullptr, xi);

  schnet_core<<<1024, 256, 0, stream>>>(f_ij, c_ij, mask, Wt0, Wt1, Wt2,
                                        b_f0, b_f1, b_f2, xi, yb);

  dense_ssp<<<256, 512, 0, stream>>>(yb, Wa0, b_a0, nullptr, y1);
  dense_ssp<<<256, 512, 0, stream>>>(y1, Wa1, b_a1, x, out);
}

// Round 3
// 113.284 us; speedup vs baseline: 1.0442x; 1.0442x over previous
//
#include <hip/hip_runtime.h>
#include <hip/hip_bf16.h>

// LoRAModulatedSchnetInteraction: B=2, A=512, F=128, Rbf=64, R=4
// Strategy:
//  - Fold LoRA into per-batch effective weights: Weff[b] = W + A[b]@B[b]  (prep_weights)
//  - x_i / final two atomwise layers: exact fp32 VALU dense kernels (dense_ssp)
//  - Core: fused per-(b,i,half) kernel: compact active j (mask), 3-layer bf16-MFMA MLP
//    on f_ij rows, * c_ij * x_i[j,:], masked sum over j -> partial y  (schnet_core)
//  - R2: exp2/log2 via __builtin_amdgcn_* (glibc header clash with __exp2f);
//    per-GEMM weight loads (opaque ptr) + launch_bounds(256,4); biases in LDS
//    pre-scaled by log2e; j-split x2.

typedef float        f32x4  __attribute__((ext_vector_type(4)));
typedef unsigned int u32x4  __attribute__((ext_vector_type(4)));
typedef unsigned int u32x2  __attribute__((ext_vector_type(2)));
typedef __bf16       bf16x8 __attribute__((ext_vector_type(8)));

__device__ __forceinline__ float ssp_pre(float acc, float bpre) {
  // ssp(acc + b) with bpre = b*log2e:  ln2 * log2(0.5*2^(acc*log2e + bpre) + 0.5)
  float t = __builtin_amdgcn_exp2f(__builtin_fmaf(acc, 1.44269504089f, bpre));
  return 0.69314718056f * __builtin_amdgcn_logf(__builtin_fmaf(t, 0.5f, 0.5f));
}

__device__ __forceinline__ float ssp_f(float v) {
  float t = __builtin_amdgcn_exp2f(v * 1.44269504089f);
  return 0.69314718056f * __builtin_amdgcn_logf(__builtin_fmaf(t, 0.5f, 0.5f));
}

__device__ __forceinline__ unsigned short f2bfu(float f) {
  __hip_bfloat16 h = __float2bfloat16(f);
  return __builtin_bit_cast(unsigned short, h);
}

__device__ __forceinline__ u32x4 pack8(f32x4 a, f32x4 b) {
  u32x4 u;
  u.x = (unsigned)f2bfu(a.x) | ((unsigned)f2bfu(a.y) << 16);
  u.y = (unsigned)f2bfu(a.z) | ((unsigned)f2bfu(a.w) << 16);
  u.z = (unsigned)f2bfu(b.x) | ((unsigned)f2bfu(b.y) << 16);
  u.w = (unsigned)f2bfu(b.z) | ((unsigned)f2bfu(b.w) << 16);
  return u;
}

__device__ __forceinline__ f32x4 fzero4() { f32x4 z = {0.f, 0.f, 0.f, 0.f}; return z; }

#define SWZ(j) (((j) & 7) << 4)

// ---------------------------------------------------------------------------
// Weight prep: Weff[b] = W + A[b] @ B[b].
// Filter layers (l=1,2,3) stored TRANSPOSED bf16 [b][nout][din] for MFMA A-frags.
// bc/a0/a1 (l=0,4,5) stored fp32 [b][k][n] for the VALU dense kernels.
// ---------------------------------------------------------------------------
__global__ void prep_weights(
    const float* __restrict__ W_bc, const float* __restrict__ A_bc, const float* __restrict__ B_bc,
    const float* __restrict__ W_f0, const float* __restrict__ A_f0, const float* __restrict__ B_f0,
    const float* __restrict__ W_f1, const float* __restrict__ A_f1, const float* __restrict__ B_f1,
    const float* __restrict__ W_f2, const float* __restrict__ A_f2, const float* __restrict__ B_f2,
    const float* __restrict__ W_a0, const float* __restrict__ A_a0, const float* __restrict__ B_a0,
    const float* __restrict__ W_a1, const float* __restrict__ A_a1, const float* __restrict__ B_a1,
    unsigned short* __restrict__ Wt0, unsigned short* __restrict__ Wt1, unsigned short* __restrict__ Wt2,
    float* __restrict__ Wbc, float* __restrict__ Wa0, float* __restrict__ Wa1)
{
  const int l = blockIdx.y, b = blockIdx.z;
  const int e = blockIdx.x * 256 + threadIdx.x;
  const float *W, *A, *Bm; int din;
  switch (l) {
    case 0:  W = W_bc; A = A_bc; Bm = B_bc; din = 128; break;
    case 1:  W = W_f0; A = A_f0; Bm = B_f0; din = 64;  break;
    case 2:  W = W_f1; A = A_f1; Bm = B_f1; din = 128; break;
    case 3:  W = W_f2; A = A_f2; Bm = B_f2; din = 128; break;
    case 4:  W = W_a0; A = A_a0; Bm = B_a0; din = 128; break;
    default: W = W_a1; A = A_a1; Bm = B_a1; din = 128; break;
  }
  if (e >= din * 128) return;
  const int k = e >> 7, n = e & 127;
  float wv = W[k * 128 + n];
  #pragma unroll
  for (int r = 0; r < 4; ++r)
    wv += A[(b * din + k) * 4 + r] * Bm[(b * 4 + r) * 128 + n];
  if (l == 1)      Wt0[(b * 128 + n) * 64  + k] = f2bfu(wv);
  else if (l == 2) Wt1[(b * 128 + n) * 128 + k] = f2bfu(wv);
  else if (l == 3) Wt2[(b * 128 + n) * 128 + k] = f2bfu(wv);
  else if (l == 0) Wbc[(b * 128 + k) * 128 + n] = wv;
  else if (l == 4) Wa0[(b * 128 + k) * 128 + n] = wv;
  else             Wa1[(b * 128 + k) * 128 + n] = wv;
}

// ---------------------------------------------------------------------------
// dense_ssp: out[row,n] = ssp(sum_k (in+in2)[row,k]*W[b,k,n] + bias[n]) (+ resid)
// rows = [2*512], fp32 exact. 4 rows per block, 512 threads (1 output each).
// ---------------------------------------------------------------------------
__global__ __launch_bounds__(512) void dense_ssp(
    const float* __restrict__ in, const float* __restrict__ in2,
    const float* __restrict__ W, const float* __restrict__ bias,
    const float* __restrict__ resid, float* __restrict__ out)
{
  __shared__ float in_l[4][128];
  const int t = threadIdx.x;
  const int rg0 = blockIdx.x << 2;        // first global row of block
  const int b = rg0 >> 9;
  {
    float v = in[rg0 * 128 + t];
    if (in2) v += in2[rg0 * 128 + t];
    in_l[t >> 7][t & 127] = v;
  }
  __syncthreads();
  const int j = t >> 7, n = t & 127;
  const float* wp = W + (b << 14) + n;
  const float* ip = in_l[j];
  float acc = 0.f;
  #pragma unroll 8
  for (int k = 0; k < 128; ++k) acc += ip[k] * wp[k << 7];
  float r = ssp_f(acc + bias[n]);
  const int oi = (rg0 + j) * 128 + n;
  if (resid) r += resid[oi];
  out[oi] = r;
}

// ---------------------------------------------------------------------------
// schnet_core: grid 2048 = (b*512+i)*2 + half. 256 threads = 4 waves.
// Wave w owns nout range [w*32, w*32+32) for all GEMMs; all waves span all j.
// half h processes its share of the 64-row tiles of the compacted j-list.
// Per tile: stage f(bf16,swizzled) -> G1 -> ssp -> hbuf -> G2 -> ssp -> hbuf
//           -> G3 -> ssp -> acc_y += s_j * xi[j,f] * h3
// Weight A-frags are (re)loaded from L2 per GEMM (opaque ptr) to keep VGPR low.
// ---------------------------------------------------------------------------
__global__ __launch_bounds__(256, 4) void schnet_core(
    const float* __restrict__ f_ij, const float* __restrict__ c_ij,
    const int* __restrict__ mask,
    const unsigned short* __restrict__ Wt0, const unsigned short* __restrict__ Wt1,
    const unsigned short* __restrict__ Wt2,
    const float* __restrict__ bias0, const float* __restrict__ bias1,
    const float* __restrict__ bias2,
    const float* __restrict__ xi, float* __restrict__ ypart)
{
  __shared__ __align__(16) unsigned short fbuf[64 * 64];    // [j][k] bf16, swizzled
  __shared__ __align__(16) unsigned short hbuf[64 * 128];   // [j][nout] bf16, swizzled
  __shared__ int   jlist[576];
  __shared__ float slist[576];
  __shared__ float bias_l[384];                             // 3x128, pre-scaled by log2e
  __shared__ int cnt_s[8], base_s[8], nact_s;

  const int tid  = threadIdx.x;
  const int lane = tid & 63;
  const int w    = tid >> 6;
  const int lrow = lane & 15;
  const int lgrp = lane >> 4;
  const int g    = blockIdx.x;
  const int bi   = g >> 1;              // b*512 + i
  const int h    = g & 1;
  const int b    = bi >> 9;

  // ---- bias staging (pre-scaled so bias-add fuses into exp2 fma) ----
  for (int t = tid; t < 384; t += 256) {
    const float* bp = (t < 128) ? bias0 : (t < 256) ? bias1 : bias2;
    bias_l[t] = bp[t & 127] * 1.44269504089f;
  }

  // ---- deterministic mask compaction ----
  const int mb = bi << 9;               // (b*512+i)*512
  const int jA = tid, jB = tid + 256;
  const int   mA = mask[mb + jA]; const float cA = c_ij[mb + jA];
  const int   mB = mask[mb + jB]; const float cB = c_ij[mb + jB];
  unsigned long long balA = __ballot(mA != 0);
  unsigned long long balB = __ballot(mB != 0);
  if (lane == 0) { cnt_s[w] = __popcll(balA); cnt_s[4 + w] = __popcll(balB); }
  __syncthreads();
  if (tid == 0) {
    int s = 0;
    for (int c = 0; c < 8; ++c) { base_s[c] = s; s += cnt_s[c]; }
    nact_s = s;
  }
  __syncthreads();
  const int na = nact_s;
  const unsigned long long lm = (1ull << lane) - 1ull;
  if (mA) { int p = base_s[w]     + __popcll(balA & lm); jlist[p] = jA; slist[p] = cA; }
  if (mB) { int p = base_s[4 + w] + __popcll(balB & lm); jlist[p] = jB; slist[p] = cB; }
  if (tid < 64) { int idx = na + tid; if (idx < 576) { jlist[idx] = 0; slist[idx] = 0.f; } }
  __syncthreads();

  // ---- this half's tile range ----
  const int tiles = (na + 63) >> 6;
  const int tmid  = (tiles + 1) >> 1;
  const int t0 = h ? tmid : 0;
  const int t1 = h ? tiles : tmid;

  const int mg = w;
  float accy[2][4] = {{0.f,0.f,0.f,0.f},{0.f,0.f,0.f,0.f}};
  const float* fbase = f_ij + ((size_t)mb << 6);

  // per-wave A-frag base offsets (lane-invariant parts precomputed)
  const int wbase0 = ((b << 7) + mg * 32 + lrow) * 64  + (lgrp << 3);
  const int wbase1 = ((b << 7) + mg * 32 + lrow) * 128 + (lgrp << 3);

  for (int tt = t0; tt < t1; ++tt) {
    const int jt0 = tt << 6;
    // ---- stage f tile: 64 gathered rows x 64 f32 -> bf16 swizzled LDS ----
    {
      const int r = tid >> 2, part = tid & 3;
      const int ja = jlist[jt0 + r];
      const f32x4* src = (const f32x4*)(fbase + ja * 64 + part * 16);
      f32x4 v0 = src[0], v1 = src[1], v2 = src[2], v3 = src[3];
      char* dst = (char*)fbuf + r * 128;
      const int o0 = (part * 32) ^ SWZ(r);
      *(u32x4*)(dst + o0)        = pack8(v0, v1);
      *(u32x4*)(dst + (o0 ^ 16)) = pack8(v2, v3);
    }
    __syncthreads();

    f32x4 acc[2][4];

    // ---- GEMM1: h1^T = Wt0 * f^T (K=64) ----
    {
      const unsigned short* wp = Wt0 + wbase0;
      asm volatile("" : "+v"(wp));        // defeat LICM: keep loads in-loop
      bf16x8 wf[2][2];
      #pragma unroll
      for (int nt = 0; nt < 2; ++nt)
        #pragma unroll
        for (int ks = 0; ks < 2; ++ks)
          wf[nt][ks] = *(const bf16x8*)(wp + nt * (16 * 64) + ks * 32);
      #pragma unroll
      for (int nt = 0; nt < 2; ++nt)
        #pragma unroll
        for (int jt = 0; jt < 4; ++jt) acc[nt][jt] = fzero4();
      #pragma unroll
      for (int jt = 0; jt < 4; ++jt) {
        const int j = jt * 16 + lrow;
        const char* rb = (const char*)fbuf + j * 128;
        const int sw = SWZ(j);
        #pragma unroll
        for (int ks = 0; ks < 2; ++ks) {
          bf16x8 bf = *(const bf16x8*)(rb + ((lgrp * 16 + ks * 64) ^ sw));
          acc[0][jt] = __builtin_amdgcn_mfma_f32_16x16x32_bf16(wf[0][ks], bf, acc[0][jt], 0, 0, 0);
          acc[1][jt] = __builtin_amdgcn_mfma_f32_16x16x32_bf16(wf[1][ks], bf, acc[1][jt], 0, 0, 0);
        }
      }
    }
    // epilogue 1: ssp -> bf16 -> hbuf
    {
      f32x4 bp0 = *(const f32x4*)(bias_l +       mg * 32 + 0  + lgrp * 4);
      f32x4 bp1 = *(const f32x4*)(bias_l +       mg * 32 + 16 + lgrp * 4);
      #pragma unroll
      for (int jt = 0; jt < 4; ++jt) {
        const int j = jt * 16 + lrow;
        char* rb = (char*)hbuf + j * 256;
        const int sw = SWZ(j);
        #pragma unroll
        for (int nt = 0; nt < 2; ++nt) {
          const int n0 = mg * 32 + nt * 16 + lgrp * 4;
          const f32x4 bp = nt ? bp1 : bp0;
          float e0 = ssp_pre(acc[nt][jt].x, bp.x);
          float e1 = ssp_pre(acc[nt][jt].y, bp.y);
          float e2 = ssp_pre(acc[nt][jt].z, bp.z);
          float e3 = ssp_pre(acc[nt][jt].w, bp.w);
          u32x2 pk;
          pk.x = (unsigned)f2bfu(e0) | ((unsigned)f2bfu(e1) << 16);
          pk.y = (unsigned)f2bfu(e2) | ((unsigned)f2bfu(e3) << 16);
          *(u32x2*)(rb + ((n0 * 2) ^ sw)) = pk;
        }
      }
    }
    __syncthreads();

    // ---- GEMM2: h2^T = Wt1 * h1^T (K=128) ----
    {
      const unsigned short* wp = Wt1 + wbase1;
      asm volatile("" : "+v"(wp));
      bf16x8 wf[2][4];
      #pragma unroll
      for (int nt = 0; nt < 2; ++nt)
        #pragma unroll
        for (int ks = 0; ks < 4; ++ks)
          wf[nt][ks] = *(const bf16x8*)(wp + nt * (16 * 128) + ks * 32);
      #pragma unroll
      for (int nt = 0; nt < 2; ++nt)
        #pragma unroll
        for (int jt = 0; jt < 4; ++jt) acc[nt][jt] = fzero4();
      #pragma unroll
      for (int jt = 0; jt < 4; ++jt) {
        const int j = jt * 16 + lrow;
        const char* rb = (const char*)hbuf + j * 256;
        const int sw = SWZ(j);
        #pragma unroll
        for (int ks = 0; ks < 4; ++ks) {
          bf16x8 bf = *(const bf16x8*)(rb + ((lgrp * 16 + ks * 64) ^ sw));
          acc[0][jt] = __builtin_amdgcn_mfma_f32_16x16x32_bf16(wf[0][ks], bf, acc[0][jt], 0, 0, 0);
          acc[1][jt] = __builtin_amdgcn_mfma_f32_16x16x32_bf16(wf[1][ks], bf, acc[1][jt], 0, 0, 0);
        }
      }
    }
    __syncthreads();   // all h1 reads done before overwrite
    // epilogue 2: ssp -> bf16 -> hbuf
    {
      f32x4 bp0 = *(const f32x4*)(bias_l + 128 + mg * 32 + 0  + lgrp * 4);
      f32x4 bp1 = *(const f32x4*)(bias_l + 128 + mg * 32 + 16 + lgrp * 4);
      #pragma unroll
      for (int jt = 0; jt < 4; ++jt) {
        const int j = jt * 16 + lrow;
        char* rb = (char*)hbuf + j * 256;
        const int sw = SWZ(j);
        #pragma unroll
        for (int nt = 0; nt < 2; ++nt) {
          const int n0 = mg * 32 + nt * 16 + lgrp * 4;
          const f32x4 bp = nt ? bp1 : bp0;
          float e0 = ssp_pre(acc[nt][jt].x, bp.x);
          float e1 = ssp_pre(acc[nt][jt].y, bp.y);
          float e2 = ssp_pre(acc[nt][jt].z, bp.z);
          float e3 = ssp_pre(acc[nt][jt].w, bp.w);
          u32x2 pk;
          pk.x = (unsigned)f2bfu(e0) | ((unsigned)f2bfu(e1) << 16);
          pk.y = (unsigned)f2bfu(e2) | ((unsigned)f2bfu(e3) << 16);
          *(u32x2*)(rb + ((n0 * 2) ^ sw)) = pk;
        }
      }
    }
    __syncthreads();

    // ---- GEMM3: h3^T = Wt2 * h2^T (K=128) ----
    {
      const unsigned short* wp = Wt2 + wbase1;
      asm volatile("" : "+v"(wp));
      bf16x8 wf[2][4];
      #pragma unroll
      for (int nt = 0; nt < 2; ++nt)
        #pragma unroll
        for (int ks = 0; ks < 4; ++ks)
          wf[nt][ks] = *(const bf16x8*)(wp + nt * (16 * 128) + ks * 32);
      #pragma unroll
      for (int nt = 0; nt < 2; ++nt)
        #pragma unroll
        for (int jt = 0; jt < 4; ++jt) acc[nt][jt] = fzero4();
      #pragma unroll
      for (int jt = 0; jt < 4; ++jt) {
        const int j = jt * 16 + lrow;
        const char* rb = (const char*)hbuf + j * 256;
        const int sw = SWZ(j);
        #pragma unroll
        for (int ks = 0; ks < 4; ++ks) {
          bf16x8 bf = *(const bf16x8*)(rb + ((lgrp * 16 + ks * 64) ^ sw));
          acc[0][jt] = __builtin_amdgcn_mfma_f32_16x16x32_bf16(wf[0][ks], bf, acc[0][jt], 0, 0, 0);
          acc[1][jt] = __builtin_amdgcn_mfma_f32_16x16x32_bf16(wf[1][ks], bf, acc[1][jt], 0, 0, 0);
        }
      }
    }
    // epilogue 3: ssp; acc_y += s_j * xi[j,f] * h3
    {
      f32x4 bp0 = *(const f32x4*)(bias_l + 256 + mg * 32 + 0  + lgrp * 4);
      f32x4 bp1 = *(const f32x4*)(bias_l + 256 + mg * 32 + 16 + lgrp * 4);
      #pragma unroll
      for (int jt = 0; jt < 4; ++jt) {
        const int jj = jt * 16 + lrow;
        const float s  = slist[jt0 + jj];
        const int   ja = jlist[jt0 + jj];
        const float* xr = xi + (((b << 9) + ja) << 7);
        #pragma unroll
        for (int nt = 0; nt < 2; ++nt) {
          const int n0 = mg * 32 + nt * 16 + lgrp * 4;
          const f32x4 bp = nt ? bp1 : bp0;
          f32x4 xv = *(const f32x4*)(xr + n0);
          float h0 = ssp_pre(acc[nt][jt].x, bp.x);
          float h1 = ssp_pre(acc[nt][jt].y, bp.y);
          float h2 = ssp_pre(acc[nt][jt].z, bp.z);
          float h3 = ssp_pre(acc[nt][jt].w, bp.w);
          accy[nt][0] += s * xv.x * h0;
          accy[nt][1] += s * xv.y * h1;
          accy[nt][2] += s * xv.z * h2;
          accy[nt][3] += s * xv.w * h3;
        }
      }
    }
    __syncthreads();   // protect fbuf/hbuf before next tile's stage
  }

  // ---- reduce over the 16 j-sub-lanes; write partial y ----
  #pragma unroll
  for (int d = 1; d < 16; d <<= 1)
    #pragma unroll
    for (int nt = 0; nt < 2; ++nt)
      #pragma unroll
      for (int r = 0; r < 4; ++r)
        accy[nt][r] += __shfl_xor(accy[nt][r], d, 64);
  if (lrow == 0) {
    float* yo = ypart + ((size_t)h << 17) + ((size_t)bi << 7);
    #pragma unroll
    for (int nt = 0; nt < 2; ++nt) {
      const int n0 = mg * 32 + nt * 16 + lgrp * 4;
      f32x4 v = {accy[nt][0], accy[nt][1], accy[nt][2], accy[nt][3]};
      *(f32x4*)(yo + n0) = v;
    }
  }
}

// ---------------------------------------------------------------------------
extern "C" void kernel_launch(void* const* d_in, const int* in_sizes, int n_in,
                              void* d_out, int out_size, void* d_ws, size_t ws_size,
                              hipStream_t stream)
{
  const float* x    = (const float*)d_in[0];
  const float* f_ij = (const float*)d_in[1];
  const float* c_ij = (const float*)d_in[2];
  const int*   mask = (const int*)d_in[3];
  const float* W_bc = (const float*)d_in[4];
  const float* b_bc = (const float*)d_in[5];
  const float* A_bc = (const float*)d_in[6];
  const float* B_bc = (const float*)d_in[7];
  const float* W_f0 = (const float*)d_in[8];
  const float* b_f0 = (const float*)d_in[9];
  const float* A_f0 = (const float*)d_in[10];
  const float* B_f0 = (const float*)d_in[11];
  const float* W_f1 = (const float*)d_in[12];
  const float* b_f1 = (const float*)d_in[13];
  const float* A_f1 = (const float*)d_in[14];
  const float* B_f1 = (const float*)d_in[15];
  const float* W_f2 = (const float*)d_in[16];
  const float* b_f2 = (const float*)d_in[17];
  const float* A_f2 = (const float*)d_in[18];
  const float* B_f2 = (const float*)d_in[19];
  const float* W_a0 = (const float*)d_in[20];
  const float* b_a0 = (const float*)d_in[21];
  const float* A_a0 = (const float*)d_in[22];
  const float* B_a0 = (const float*)d_in[23];
  const float* W_a1 = (const float*)d_in[24];
  const float* b_a1 = (const float*)d_in[25];
  const float* A_a1 = (const float*)d_in[26];
  const float* B_a1 = (const float*)d_in[27];
  float* out = (float*)d_out;

  char* ws = (char*)d_ws;
  unsigned short* Wt0 = (unsigned short*)(ws);            //  32768 B
  unsigned short* Wt1 = (unsigned short*)(ws + 32768);    //  65536 B
  unsigned short* Wt2 = (unsigned short*)(ws + 98304);    //  65536 B
  float* Wbc = (float*)(ws + 163840);                     // 131072 B
  float* Wa0 = (float*)(ws + 294912);                     // 131072 B
  float* Wa1 = (float*)(ws + 425984);                     // 131072 B
  float* xi  = (float*)(ws + 557056);                     // 524288 B
  float* yp  = (float*)(ws + 1081344);                    // 2 x 524288 B
  float* y1  = (float*)(ws + 2129920);                    // 524288 B (total ~2.65 MB)

  prep_weights<<<dim3(64, 6, 2), 256, 0, stream>>>(
      W_bc, A_bc, B_bc, W_f0, A_f0, B_f0, W_f1, A_f1, B_f1,
      W_f2, A_f2, B_f2, W_a0, A_a0, B_a0, W_a1, A_a1, B_a1,
      Wt0, Wt1, Wt2, Wbc, Wa0, Wa1);

  dense_ssp<<<256, 512, 0, stream>>>(x, nullptr, Wbc, b_bc, nullptr, xi);

  schnet_core<<<2048, 256, 0, stream>>>(f_ij, c_ij, mask, Wt0, Wt1, Wt2,
                                        b_f0, b_f1, b_f2, xi, yp);

  dense_ssp<<<256, 512, 0, stream>>>(yp, yp + (1 << 17), Wa0, b_a0, nullptr, y1);
  dense_ssp<<<256, 512, 0, stream>>>(y1, nullptr, Wa1, b_a1, x, out);
}